// Round 19
// baseline (238.114 us; speedup 1.0000x reference)
//
#include <hip/hip_runtime.h>
#include <hip/hip_bf16.h>

#define Bq 4
#define Sq 2048
#define Dq 1024
#define Hq 16
#define HDq 64
#define Mq (Bq*Sq)   // 8192

typedef unsigned short u16;
typedef __attribute__((ext_vector_type(8))) __bf16 b16x8;
typedef __attribute__((ext_vector_type(4))) float f32x4;
typedef __attribute__((ext_vector_type(4))) unsigned int u32x4;

__device__ inline float bf2f(u16 h){ union{unsigned u; float f;} v; v.u = ((unsigned)h)<<16; return v.f; }
__device__ inline u16 f2bf(float f){ union{float f; unsigned u;} v; v.f=f; unsigned r = v.u + 0x7FFFu + ((v.u>>16)&1u); return (u16)(r>>16); }
__device__ inline u16 truncbf(float f){ union{float f; unsigned u;} v; v.f=f; return (u16)(v.u>>16); }
__device__ inline float ld_elem(const void* p, size_t i, int isf32){
  return isf32 ? ((const float*)p)[i] : bf2f(((const u16*)p)[i]);
}
// async global->LDS, 16B per lane; LDS dest must be wave-uniform-base + lane*16
__device__ inline void ld16(const u16* g, u16* l){
  __builtin_amdgcn_global_load_lds((const __attribute__((address_space(1))) void*)g,
                                   (__attribute__((address_space(3))) void*)l, 16, 0, 0);
}

#if __has_builtin(__builtin_amdgcn_exp2f)
#define EXP2(x) __builtin_amdgcn_exp2f(x)
#else
#define EXP2(x) __expf((x)*0.69314718056f)
#endif
// 0.125 (1/sqrt(64)) * log2(e): folded into Q in the QKV-gemm epilogue.
#define SCALE_LOG2E 0.18033688011112042f

// ---- per-wave dtype detection (verified r12-r18): wave ballots on bf16-exponent
// fields of x's first 256 words. fp32 N(0,1) -> ~28/64 hits; bf16 -> 0. Thr 8.
__device__ inline int detect_wave(const unsigned* __restrict__ x, int t){
  unsigned w = x[t & 255];
  unsigned long long m1 = __ballot(((w>>7)&0xFFu)>=0x90u);
  unsigned long long m2 = __ballot(((w>>23)&0xFFu)>=0x90u);
  return (__popcll(m1)+__popcll(m2)) > 8 ? 1 : 0;
}

// ---- fused preamble (verified r12-r18): x->bf16 convert (blocks 0..4095) +
// W transpose (4096..5119).
__global__ __launch_bounds__(256) void prep(
    const void* __restrict__ x,
    const void* __restrict__ W0, const void* __restrict__ W1,
    const void* __restrict__ W2, const void* __restrict__ W3,
    u16* __restrict__ xc,
    u16* __restrict__ T0, u16* __restrict__ T1,
    u16* __restrict__ T2, u16* __restrict__ T3){
  __shared__ u16 tile[64][65];
  const int t = threadIdx.x;
  const int f = detect_wave((const unsigned*)x, t);
  const int bid = blockIdx.x;
  if (bid < 4096){
    int i = (bid*256 + t)*8;                     // covers Mq*Dq exactly
    if(f){
      const float* xf=(const float*)x;
      #pragma unroll
      for(int j=0;j<8;j++) xc[i+j] = f2bf(xf[i+j]);
    } else {
      *(u32x4*)&xc[i] = *(const u32x4*)((const u16*)x + i);
    }
  } else {
    int idx = bid - 4096;                        // [0,1024)
    int z = idx >> 8, rem = idx & 255;
    int k0 = (rem & 15)*64, n0 = (rem >> 4)*64;
    const void* src = (z==0)?W0:(z==1)?W1:(z==2)?W2:W3;
    u16*       dst = (z==0)?T0:(z==1)?T1:(z==2)?T2:T3;
    #pragma unroll
    for(int r=0;r<16;r++){
      int row = r*4 + (t>>6), col = t&63;
      tile[row][col] = f2bf(ld_elem(src, (size_t)(k0+row)*Dq + n0 + col, f));
    }
    __syncthreads();
    #pragma unroll
    for(int r=0;r<16;r++){
      int row = r*4 + (t>>6), col = t&63;
      dst[(size_t)(n0+row)*Dq + k0 + col] = tile[col][row];
    }
  }
}

// -------- GEMM v14 (QKV): 1-WAVE BLOCK, barrier-free, ZERO duplication --------
// The untested quadrant of the session's cost law. Measured regimes:
//   barriered:    4.26 B/cyc/block (any per-step rendezvous = max-over-waves; r17
//                 proved barrier COUNT is irrelevant, the rendezvous is the cost)
//   barrier-free: ~10.2 B/cyc/block, ~20.3 B/cyc/CU (r11) -- but r11 paid 2x dup.
// This cell gets barrier-free WITHOUT duplication: ONE wave owns a full 128^2
// tile. acc[8][8]=256 VGPR + af/bf 64 + temps ~ 350 (< 450 no-spill, m08/m24)
// -> 1 wave/SIMD -> 4 independent blocks/CU; LDS ring-2 32KB/block = 128KB/CU.
// Staged bytes = 786 MB total (1 instr/KB, identical to r8, no dup).
// Single-wave ledger (pure program order, no s_barrier anywhere):
//   iter tt: issue 16 gload_lds for tile tt+1 (slot s^1); vmcnt(16) -> tile tt's
//   16 landed (in-order, m135), tt+1 in flight; ds_read af[8]/bf[8]; lgkm0 +
//   sched_barrier (rule #18); 64 MFMA. WAR: slot s^1's reads retired at iter
//   tt-1's lgkm0, which precedes these stages in program order.
// Predict: 786MB / (20.3 B/cyc x 256 CU) ~ 63-80us if the CU-level barrier-free
// rate holds at 4 fat waves. Falsifier: >=100us -> rate is per-wave-capped,
// quadrant closes, restore r18.
__global__ __launch_bounds__(64) void gemm_1w(
    const u16* __restrict__ A, const u16* __restrict__ Bt,
    u16* __restrict__ O0, u16* __restrict__ O1, u16* __restrict__ O2){
  constexpr int NT = Dq/32;                      // 32 K-steps
  __shared__ u16 Asl[2][128*32];                 // 2 x 8KB
  __shared__ u16 Bsl[2][128*32];                 // 2 x 8KB -> 32KB
  const int lane = threadIdx.x;                  // 64 threads = 1 wave
  const int quad = lane >> 4, l16 = lane & 15;
  // T1 XCD-chunked remap (identical map to the r8 MODE0 cell; nwg=1536, %8==0)
  int L = blockIdx.x + blockIdx.y*gridDim.x;
  int k8 = L & 7, ii = L >> 3;
  int nsb = ii >> 6, rem = ii & 63;
  int mg = rem >> 3, ng = rem & 7;
  const int m0 = (k8*8 + mg)*128, n0 = (nsb*8 + ng)*128;

  f32x4 acc[8][8] = {};                          // 256 VGPR accumulator

  auto stageA = [&](int T, int s){               // 8 loads/lane, 8KB panel
    #pragma unroll
    for(int r=0;r<8;r++){
      int idx = lane + (r<<6);                   // 0..511 16B-slots
      int row = idx>>2, g = idx&3;
      int gl = g ^ ((row>>1)&3);
      ld16(&A[(size_t)(m0+row)*Dq + (T<<5) + gl*8], &Asl[s][idx*8]);
    }
  };
  auto stageB = [&](int T, int s){               // 8 loads/lane, 8KB panel
    #pragma unroll
    for(int r=0;r<8;r++){
      int idx = lane + (r<<6);
      int row = idx>>2, g = idx&3;
      int gl = g ^ ((row>>1)&3);
      ld16(&Bt[(size_t)(n0+row)*Dq + (T<<5) + gl*8], &Bsl[s][idx*8]);
    }
  };
  auto ldA = [&](int s, int i)->b16x8{
    int row = i*16 + l16;                        // [0,128)
    return *(const b16x8*)&Asl[s][row*32 + ((quad ^ ((row>>1)&3))<<3)];
  };
  auto ldB = [&](int s, int j)->b16x8{
    int row = j*16 + l16;                        // [0,128)
    return *(const b16x8*)&Bsl[s][row*32 + ((quad ^ ((row>>1)&3))<<3)];
  };
  #define MFMA_BF16 __builtin_amdgcn_mfma_f32_16x16x32_bf16

  stageA(0,0); stageB(0,0);                      // 16 loads in flight

  for(int tt=0; tt<NT; ++tt){
    const int s = tt&1;
    if(tt+1<NT){
      stageA(tt+1, s^1); stageB(tt+1, s^1);      // outstanding {tt:16, tt+1:16}
      asm volatile("s_waitcnt vmcnt(16)" ::: "memory");  // tile tt landed
    } else {
      asm volatile("s_waitcnt vmcnt(0)" ::: "memory");
    }
    __builtin_amdgcn_sched_barrier(0);
    b16x8 af[8], bf[8];
    #pragma unroll
    for(int i=0;i<8;i++) af[i]=ldA(s,i);
    #pragma unroll
    for(int j=0;j<8;j++) bf[j]=ldB(s,j);
    asm volatile("s_waitcnt lgkmcnt(0)" ::: "memory");
    __builtin_amdgcn_sched_barrier(0);           // rule #18: pin MFMA after lgkm
    #pragma unroll
    for(int i=0;i<8;i++)
      #pragma unroll
      for(int j=0;j<8;j++)
        acc[i][j]=MFMA_BF16(af[i],bf[j],acc[i][j],0,0,0);
    // no barrier: WAR for slot s^1 is program-order (reads retired at lgkm0 above)
  }

  // epilogue: scatter Q (pre-scaled) / K / VT
  #pragma unroll
  for(int i=0;i<8;i++){
    #pragma unroll
    for(int j=0;j<8;j++){
      int n = n0 + j*16 + l16;
      #pragma unroll
      for(int r=0;r<4;r++){
        int m = m0 + i*16 + quad*4 + r;           // C/D: row=quad*4+reg, col=l16
        float c = acc[i][j][r];
        int z = n >> 10, nn2 = n & 1023;
        int b = m >> 11, s2x = m & 2047;
        int h = nn2 >> 6, hd = nn2 & 63;
        if (z==0)      O0[(((size_t)(b*Hq + h))*Sq + s2x)*HDq + hd] = f2bf(c*SCALE_LOG2E);
        else if (z==1) O1[(((size_t)(b*Hq + h))*Sq + s2x)*HDq + hd] = f2bf(c);
        else           O2[(((size_t)(b*Hq + h))*HDq + hd)*Sq + s2x] = f2bf(c);
      }
    }
  }
  #undef MFMA_BF16
}

// ---------------- GEMM out-proj: r8/r16 proven cell, verbatim ----------------
// (512-tile grid would under-fill the 1-wave design's 1024 wave-slots; stays here.)
__global__ __launch_bounds__(256, 3) void gemm_op(
    const u16* __restrict__ A, const u16* __restrict__ Bt,
    void* __restrict__ Og, const void* __restrict__ bias,
    const unsigned* __restrict__ xdet){
  constexpr int NT = Dq/32;                      // 32 K-tiles (BK=32)
  __shared__ u16 Asl[3][128*32];
  __shared__ u16 Bsl[3][128*32];                 // 48KB total
  const int f = detect_wave(xdet, threadIdx.x);
  const int t = threadIdx.x;
  const int lane = t & 63, wave = t >> 6;        // 4 waves
  const int quad = lane >> 4, l16 = lane & 15;
  const int wr = wave >> 1, wc = wave & 1;       // 2M x 2N
  int L = blockIdx.x + blockIdx.y*gridDim.x;
  int k8 = L & 7, ii = L >> 3;
  int mg = ii >> 3, ng = ii & 7;                 // per XCD 64 = 8m x 8n
  const int m0 = (k8*8 + mg)*128, n0 = ng*128;

  f32x4 acc[4][4] = {};

  auto stageA = [&](int T, int s){
    #pragma unroll
    for(int r=0;r<2;r++){
      int idx = t + (r<<8);
      int row = idx>>2, g = idx&3;
      int gl = g ^ ((row>>1)&3);
      ld16(&A[(size_t)(m0+row)*Dq + (T<<5) + gl*8], &Asl[s][idx*8]);
    }
  };
  auto stageB = [&](int T, int s){
    #pragma unroll
    for(int r=0;r<2;r++){
      int idx = t + (r<<8);
      int row = idx>>2, g = idx&3;
      int gl = g ^ ((row>>1)&3);
      ld16(&Bt[(size_t)(n0+row)*Dq + (T<<5) + gl*8], &Bsl[s][idx*8]);
    }
  };
  auto ldA = [&](int s, int i)->b16x8{
    int row = wr*64 + i*16 + l16;
    return *(const b16x8*)&Asl[s][row*32 + ((quad ^ ((row>>1)&3))<<3)];
  };
  auto ldB = [&](int s, int j)->b16x8{
    int row = wc*64 + j*16 + l16;
    return *(const b16x8*)&Bsl[s][row*32 + ((quad ^ ((row>>1)&3))<<3)];
  };
  #define MFMA_BF16 __builtin_amdgcn_mfma_f32_16x16x32_bf16

  stageA(0,0); stageB(0,0); stageA(1,1); stageB(1,1);
  asm volatile("s_waitcnt vmcnt(4)" ::: "memory");
  __builtin_amdgcn_s_barrier();
  __builtin_amdgcn_sched_barrier(0);

  int s0=0, s1=1, s2=2;
  for(int tt=0; tt<NT; ++tt){
    if(tt+2<NT){ stageA(tt+2, s2); stageB(tt+2, s2); }
    b16x8 af[4], bf[4];
    #pragma unroll
    for(int i=0;i<4;i++) af[i]=ldA(s0,i);
    #pragma unroll
    for(int j=0;j<4;j++) bf[j]=ldB(s0,j);
    __builtin_amdgcn_s_barrier();
    asm volatile("s_waitcnt lgkmcnt(0)" ::: "memory");
    __builtin_amdgcn_sched_barrier(0);
    __builtin_amdgcn_s_setprio(1);
    #pragma unroll
    for(int i=0;i<4;i++)
      #pragma unroll
      for(int j=0;j<4;j++)
        acc[i][j]=MFMA_BF16(af[i],bf[j],acc[i][j],0,0,0);
    __builtin_amdgcn_s_setprio(0);
    if(tt<NT-2) asm volatile("s_waitcnt vmcnt(4)" ::: "memory");
    else        asm volatile("s_waitcnt vmcnt(0)" ::: "memory");
    __builtin_amdgcn_s_barrier();
    __builtin_amdgcn_sched_barrier(0);
    int x2=s0; s0=s1; s1=s2; s2=x2;
  }

  #pragma unroll
  for(int i=0;i<4;i++){
    #pragma unroll
    for(int j=0;j<4;j++){
      int n = n0 + wc*64 + j*16 + l16;
      #pragma unroll
      for(int r=0;r<4;r++){
        int m = m0 + wr*64 + i*16 + quad*4 + r;
        float c2 = acc[i][j][r] + ld_elem(bias, n, f);
        if (f) ((float*)Og)[(size_t)m*Dq + n] = c2;
        else   ((u16*)Og)[(size_t)m*Dq + n]   = f2bf(c2);
      }
    }
  }
  #undef MFMA_BF16
}

// ---------------- flash attention v10 (r16 winner, verbatim): 4 q-tiles/block ----------
__global__ __launch_bounds__(256) void flash_attn(
    const u16* __restrict__ Q, const u16* __restrict__ K,
    const u16* __restrict__ VT, u16* __restrict__ C){
  __shared__ u16 Kt[128*64];    // [key][hd], 8 groups/row swizzled
  __shared__ u16 Vt[64*128];    // [hd][key], 16 groups/row swizzled
  __shared__ u16 Pl[4][16][72]; // per-wave P round-trip (C-layout -> A-layout)
  const int t = threadIdx.x;
  const int lane = t&63, wave = t>>6, quad = lane>>4, l16 = lane&15;
  // T1 remap: grid (8, 64) = 512; L&7 = XCD; per-XCD chunk = 8 bh x 8 p.
  int L  = blockIdx.x + blockIdx.y*gridDim.x;
  int k8 = L & 7, ii = L >> 3;           // ii in [0,64)
  const int bh = k8*8 + (ii>>3);
  const int p  = ii & 7;                 // [0,8)
  const int b = bh >> 4, h = bh & 15;
  const int qt[4] = { p, 15-p, 16+p, 31-p };
  int nk[4];
  #pragma unroll
  for(int tt=0;tt<4;tt++){ int v = qt[tt]+2; nk[tt] = (v<32)?v:32; }
  const int nrounds = (nk[3]+1)>>1;      // qt[3]=31-p is the max
  const u16* Qh = Q  + (size_t)bh*Sq*HDq;
  const u16* Kh = K  + (size_t)bh*Sq*HDq;
  const u16* Vh = VT + (size_t)bh*HDq*Sq;

  b16x8 aq[4][2];
  #pragma unroll
  for(int tt=0;tt<4;tt++){
    const u16* qp = Qh + (size_t)(qt[tt]*64 + wave*16 + l16)*HDq + quad*8;
    aq[tt][0] = *(const b16x8*)qp;
    aq[tt][1] = *(const b16x8*)(qp + 32);
  }
  b16x8 vone;
  #pragma unroll
  for(int i=0;i<8;i++) vone[i] = (__bf16)1.0f;

  const f32x4 fzero = {0.f,0.f,0.f,0.f};
  f32x4 Oa[4][4]; f32x4 lacc[4];
  #pragma unroll
  for(int tt=0;tt<4;tt++){ lacc[tt]=fzero; for(int j=0;j<4;j++) Oa[tt][j]=fzero; }

  for(int kt2=0; kt2<nrounds; kt2++){
    __syncthreads();
    #pragma unroll
    for(int r=0;r<4;r++){
      int idx = t + (r<<8);            // K slots 0..1023
      int row = idx>>3, g = idx&7;
      int csw = (g ^ (row&7))<<3;
      ld16(Kh + (size_t)(kt2*128+row)*HDq + csw, Kt + idx*8);
    }
    #pragma unroll
    for(int r=0;r<4;r++){
      int idx = t + (r<<8);            // V slots 0..1023
      int row = idx>>4, g = idx&15;    // 64 hd-rows x 16 groups
      int csw = (g ^ (row&15))<<3;
      ld16(Vh + (size_t)row*Sq + (size_t)kt2*128 + csw, Vt + idx*8);
    }
    __syncthreads();

    #pragma unroll
    for(int half=0; half<2; half++){
      const int kt = kt2*2 + half;
      #pragma unroll
      for(int tt=0;tt<4;tt++){
        if (kt >= nk[tt]) continue;            // wave-uniform skip
        const int qq0 = qt[tt]*64;
        f32x4 sc[4];
        #pragma unroll
        for(int jn=0;jn<4;jn++){
          int krow = half*64 + jn*16 + l16;
          const u16* kp = &Kt[krow*64];
          f32x4 s = fzero;
          b16x8 bk0 = *(const b16x8*)&kp[((quad     ^ (krow&7))<<3)];
          b16x8 bk1 = *(const b16x8*)&kp[(((quad+4) ^ (krow&7))<<3)];
          s = __builtin_amdgcn_mfma_f32_16x16x32_bf16(aq[tt][0], bk0, s, 0,0,0);
          s = __builtin_amdgcn_mfma_f32_16x16x32_bf16(aq[tt][1], bk1, s, 0,0,0);
          sc[jn] = s;
        }
        if (kt < qt[tt]) {
          // fully unmasked tile: p = exp2(s) directly (Q carries the scale)
          #pragma unroll
          for(int jn=0;jn<4;jn++)
            #pragma unroll
            for(int r=0;r<4;r++)
              Pl[wave][quad*4+r][jn*16+l16] = truncbf(EXP2(sc[jn][r]));
        } else {
          // boundary tiles kt in {qt, qt+1}: apply causal(+1) mask
          const int qbase = qq0 + wave*16 + quad*4;
          #pragma unroll
          for(int jn=0;jn<4;jn++){
            int kg = kt*64 + jn*16 + l16;
            #pragma unroll
            for(int r=0;r<4;r++){
              float sv = sc[jn][r];
              if (kg > qbase + r + 1) sv = -__builtin_inff();   // tril(k=1): key <= q+1
              Pl[wave][quad*4+r][jn*16+l16] = truncbf(EXP2(sv));
            }
          }
        }
        // O += P V ; l += P . 1   (Pl wave-private: no barrier)
        #pragma unroll
        for(int ks=0;ks<2;ks++){
          b16x8 ap = *(const b16x8*)&Pl[wave][l16][ks*32 + quad*8];
          int glog = half*8 + ks*4 + quad;
          #pragma unroll
          for(int jd=0;jd<4;jd++){
            int hd = jd*16 + l16;
            b16x8 bv = *(const b16x8*)&Vt[hd*128 + ((glog ^ (hd&15))<<3)];
            Oa[tt][jd] = __builtin_amdgcn_mfma_f32_16x16x32_bf16(ap, bv, Oa[tt][jd], 0,0,0);
          }
          lacc[tt] = __builtin_amdgcn_mfma_f32_16x16x32_bf16(ap, vone, lacc[tt], 0,0,0);
        }
      }
    }
  }
  #pragma unroll
  for(int tt=0;tt<4;tt++){
    const int qq0 = qt[tt]*64;
    #pragma unroll
    for(int r=0;r<4;r++){
      int s = qq0 + wave*16 + quad*4 + r;
      float inv = 1.0f / lacc[tt][r];
      #pragma unroll
      for(int jd=0;jd<4;jd++)
        C[((size_t)(b*Sq + s))*Dq + h*HDq + jd*16 + l16] = f2bf(Oa[tt][jd][r]*inv);
    }
  }
}

// ---------------- launch ----------------
extern "C" void kernel_launch(void* const* d_in, const int* in_sizes, int n_in,
                              void* d_out, int out_size, void* d_ws, size_t ws_size,
                              hipStream_t stream){
  const void* x  = d_in[0];
  const void* Wq = d_in[1];
  const void* Wk = d_in[2];
  const void* Wv = d_in[3];
  const void* Wo = d_in[4];
  const void* bo = d_in[5];

  char* ws = (char*)d_ws;
  size_t off = 0;
  auto wsalloc = [&](size_t bytes)->void*{
    void* p = ws + off; off += (bytes + 255) & ~(size_t)255; return p;
  };
  // WqT/WkT/WvT contiguous: QKV-gemm sees one [3072][1024] B^T matrix
  u16* WqT = (u16*)wsalloc((size_t)Dq*Dq*2);
  u16* WkT = (u16*)wsalloc((size_t)Dq*Dq*2);
  u16* WvT = (u16*)wsalloc((size_t)Dq*Dq*2);
  u16* WoT = (u16*)wsalloc((size_t)Dq*Dq*2);
  u16* xc  = (u16*)wsalloc((size_t)Mq*Dq*2);
  u16* Qb  = (u16*)wsalloc((size_t)Mq*Dq*2);   // [b,h,s,hd], pre-scaled
  u16* Kb  = (u16*)wsalloc((size_t)Mq*Dq*2);   // [b,h,s,hd]
  u16* VTb = (u16*)wsalloc((size_t)Mq*Dq*2);   // [b,h,hd,s]
  u16* Cb  = (u16*)wsalloc((size_t)Mq*Dq*2);   // [b,s,d]

  prep<<<dim3(5120), 256, 0, stream>>>(x, Wq,Wk,Wv,Wo, xc, WqT,WkT,WvT,WoT);
  gemm_1w<<<dim3(24, 64), 64, 0, stream>>>(xc, WqT, Qb,Kb,VTb);
  flash_attn<<<dim3(8, Bq*Hq), 256, 0, stream>>>(Qb, Kb, VTb, Cb);
  gemm_op<<<dim3(8, 64), 256, 0, stream>>>(Cb, WoT, d_out, bo, (const unsigned*)x);
}

// Round 20
// 193.302 us; speedup vs baseline: 1.2318x; 1.2318x over previous
//
#include <hip/hip_runtime.h>
#include <hip/hip_bf16.h>

#define Bq 4
#define Sq 2048
#define Dq 1024
#define Hq 16
#define HDq 64
#define Mq (Bq*Sq)   // 8192

typedef unsigned short u16;
typedef __attribute__((ext_vector_type(8))) __bf16 b16x8;
typedef __attribute__((ext_vector_type(4))) float f32x4;
typedef __attribute__((ext_vector_type(4))) unsigned int u32x4;

__device__ inline float bf2f(u16 h){ union{unsigned u; float f;} v; v.u = ((unsigned)h)<<16; return v.f; }
__device__ inline u16 f2bf(float f){ union{float f; unsigned u;} v; v.f=f; unsigned r = v.u + 0x7FFFu + ((v.u>>16)&1u); return (u16)(r>>16); }
__device__ inline u16 truncbf(float f){ union{float f; unsigned u;} v; v.f=f; return (u16)(v.u>>16); }
__device__ inline float ld_elem(const void* p, size_t i, int isf32){
  return isf32 ? ((const float*)p)[i] : bf2f(((const u16*)p)[i]);
}
// async global->LDS, 16B per lane; LDS dest must be wave-uniform-base + lane*16
__device__ inline void ld16(const u16* g, u16* l){
  __builtin_amdgcn_global_load_lds((const __attribute__((address_space(1))) void*)g,
                                   (__attribute__((address_space(3))) void*)l, 16, 0, 0);
}

#if __has_builtin(__builtin_amdgcn_exp2f)
#define EXP2(x) __builtin_amdgcn_exp2f(x)
#else
#define EXP2(x) __expf((x)*0.69314718056f)
#endif
// 0.125 (1/sqrt(64)) * log2(e): folded into Q in the QKV-gemm epilogue.
#define SCALE_LOG2E 0.18033688011112042f

// ---- per-wave dtype detection (verified r12-r19): wave ballots on bf16-exponent
// fields of x's first 256 words. fp32 N(0,1) -> ~28/64 hits; bf16 -> 0. Thr 8.
__device__ inline int detect_wave(const unsigned* __restrict__ x, int t){
  unsigned w = x[t & 255];
  unsigned long long m1 = __ballot(((w>>7)&0xFFu)>=0x90u);
  unsigned long long m2 = __ballot(((w>>23)&0xFFu)>=0x90u);
  return (__popcll(m1)+__popcll(m2)) > 8 ? 1 : 0;
}

// ---- fused preamble (verified r12-r19): x->bf16 convert (blocks 0..4095) +
// W transpose (4096..5119).
__global__ __launch_bounds__(256) void prep(
    const void* __restrict__ x,
    const void* __restrict__ W0, const void* __restrict__ W1,
    const void* __restrict__ W2, const void* __restrict__ W3,
    u16* __restrict__ xc,
    u16* __restrict__ T0, u16* __restrict__ T1,
    u16* __restrict__ T2, u16* __restrict__ T3){
  __shared__ u16 tile[64][65];
  const int t = threadIdx.x;
  const int f = detect_wave((const unsigned*)x, t);
  const int bid = blockIdx.x;
  if (bid < 4096){
    int i = (bid*256 + t)*8;                     // covers Mq*Dq exactly
    if(f){
      const float* xf=(const float*)x;
      #pragma unroll
      for(int j=0;j<8;j++) xc[i+j] = f2bf(xf[i+j]);
    } else {
      *(u32x4*)&xc[i] = *(const u32x4*)((const u16*)x + i);
    }
  } else {
    int idx = bid - 4096;                        // [0,1024)
    int z = idx >> 8, rem = idx & 255;
    int k0 = (rem & 15)*64, n0 = (rem >> 4)*64;
    const void* src = (z==0)?W0:(z==1)?W1:(z==2)?W2:W3;
    u16*       dst = (z==0)?T0:(z==1)?T1:(z==2)?T2:T3;
    #pragma unroll
    for(int r=0;r<16;r++){
      int row = r*4 + (t>>6), col = t&63;
      tile[row][col] = f2bf(ld_elem(src, (size_t)(k0+row)*Dq + n0 + col, f));
    }
    __syncthreads();
    #pragma unroll
    for(int r=0;r<16;r++){
      int row = r*4 + (t>>6), col = t&63;
      dst[(size_t)(n0+row)*Dq + k0 + col] = tile[col][row];
    }
  }
}

// ---------------- GEMM: r8/r16 cell (measured-optimum, FINAL) ----------------
// Complete session cost law (20 variants): gload_lds issue is PER-WAVE-capped
// (~2-4 B/cyc/wave; barriered convoy ~1.1); CU rate scales with wave count, not
// blocks/ring-depth/barrier-count. Zero-duplication staging needs >=4 cooperating
// waves. This cell (12 waves/CU, no dup, 4.26 B/cyc/block x 3) is the optimum of
// the reachable space: r19 1-wave barrier-free 187us, r14 8-wave 110us, r11 dup
// 126us, r17 1-barrier neutral, r6/r3/r5 big-tile/8-phase all worse. FROZEN.
template<int MODE>
__global__ __launch_bounds__(256, 3) void gemm2p(
    const u16* __restrict__ A, const u16* __restrict__ Bt,
    u16* __restrict__ O0, u16* __restrict__ O1, u16* __restrict__ O2,
    void* __restrict__ Og, const void* __restrict__ bias,
    const unsigned* __restrict__ xdet){
  constexpr int NT = Dq/32;                      // 32 K-tiles (BK=32)
  __shared__ u16 Asl[3][128*32];
  __shared__ u16 Bsl[3][128*32];                 // 48KB total
  const int f = (MODE==1) ? detect_wave(xdet, threadIdx.x) : 0;
  const int t = threadIdx.x;
  const int lane = t & 63, wave = t >> 6;        // 4 waves
  const int quad = lane >> 4, l16 = lane & 15;
  const int wr = wave >> 1, wc = wave & 1;       // 2M x 2N
  // T1 XCD-chunked remap. nwg%8==0 for both grids (1536 / 512).
  int L = blockIdx.x + blockIdx.y*gridDim.x;
  int k8 = L & 7, ii = L >> 3;
  int m0, n0;
  if (MODE==0){
    // per XCD 192 = 3 n-superblocks x (8m x 8n); concurrent 2MB A + 2MB B = L2
    int nsb = ii >> 6, rem = ii & 63;
    int mg = rem >> 3, ng = rem & 7;
    m0 = (k8*8 + mg)*128; n0 = (nsb*8 + ng)*128;
  } else {
    // per XCD 64 = 8m x 8n; A 2MB + B 2MB = L2
    int mg = ii >> 3, ng = ii & 7;
    m0 = (k8*8 + mg)*128; n0 = ng*128;
  }

  f32x4 acc[4][4] = {};

  auto stageA = [&](int T, int s){               // 2 loads/thread
    #pragma unroll
    for(int r=0;r<2;r++){
      int idx = t + (r<<8);
      int row = idx>>2, g = idx&3;
      int gl = g ^ ((row>>1)&3);
      ld16(&A[(size_t)(m0+row)*Dq + (T<<5) + gl*8], &Asl[s][idx*8]);
    }
  };
  auto stageB = [&](int T, int s){               // 2 loads/thread
    #pragma unroll
    for(int r=0;r<2;r++){
      int idx = t + (r<<8);
      int row = idx>>2, g = idx&3;
      int gl = g ^ ((row>>1)&3);
      ld16(&Bt[(size_t)(n0+row)*Dq + (T<<5) + gl*8], &Bsl[s][idx*8]);
    }
  };
  auto ldA = [&](int s, int i)->b16x8{
    int row = wr*64 + i*16 + l16;
    return *(const b16x8*)&Asl[s][row*32 + ((quad ^ ((row>>1)&3))<<3)];
  };
  auto ldB = [&](int s, int j)->b16x8{
    int row = wc*64 + j*16 + l16;
    return *(const b16x8*)&Bsl[s][row*32 + ((quad ^ ((row>>1)&3))<<3)];
  };
  #define MFMA_BF16 __builtin_amdgcn_mfma_f32_16x16x32_bf16

  // prologue: tiles 0,1 (8 loads); vmcnt(4) -> tile 0 landed, tile 1 in flight.
  stageA(0,0); stageB(0,0); stageA(1,1); stageB(1,1);
  asm volatile("s_waitcnt vmcnt(4)" ::: "memory");
  __builtin_amdgcn_s_barrier();
  __builtin_amdgcn_sched_barrier(0);

  int s0=0, s1=1, s2=2;
  for(int tt=0; tt<NT; ++tt){
    if(tt+2<NT){ stageA(tt+2, s2); stageB(tt+2, s2); }
    b16x8 af[4], bf[4];
    #pragma unroll
    for(int i=0;i<4;i++) af[i]=ldA(s0,i);
    #pragma unroll
    for(int j=0;j<4;j++) bf[j]=ldB(s0,j);
    __builtin_amdgcn_s_barrier();
    asm volatile("s_waitcnt lgkmcnt(0)" ::: "memory");
    __builtin_amdgcn_sched_barrier(0);
    __builtin_amdgcn_s_setprio(1);
    #pragma unroll
    for(int i=0;i<4;i++)
      #pragma unroll
      for(int j=0;j<4;j++)
        acc[i][j]=MFMA_BF16(af[i],bf[j],acc[i][j],0,0,0);
    __builtin_amdgcn_s_setprio(0);
    if(tt<NT-2) asm volatile("s_waitcnt vmcnt(4)" ::: "memory");
    else        asm volatile("s_waitcnt vmcnt(0)" ::: "memory");
    __builtin_amdgcn_s_barrier();
    __builtin_amdgcn_sched_barrier(0);
    int x2=s0; s0=s1; s1=s2; s2=x2;
  }

  #pragma unroll
  for(int i=0;i<4;i++){
    #pragma unroll
    for(int j=0;j<4;j++){
      int n = n0 + wc*64 + j*16 + l16;
      #pragma unroll
      for(int r=0;r<4;r++){
        int m = m0 + wr*64 + i*16 + quad*4 + r;   // C/D: row=quad*4+reg, col=l16
        float c = acc[i][j][r];
        if (MODE==1){
          float c2 = c + ld_elem(bias, n, f);
          if (f) ((float*)Og)[(size_t)m*Dq + n] = c2;
          else   ((u16*)Og)[(size_t)m*Dq + n]   = f2bf(c2);
        } else {
          int z = n >> 10, nn2 = n & 1023;
          int b = m >> 11, s2x = m & 2047;
          int h = nn2 >> 6, hd = nn2 & 63;
          if (z==0)      O0[(((size_t)(b*Hq + h))*Sq + s2x)*HDq + hd] = f2bf(c*SCALE_LOG2E);
          else if (z==1) O1[(((size_t)(b*Hq + h))*Sq + s2x)*HDq + hd] = f2bf(c);
          else           O2[(((size_t)(b*Hq + h))*HDq + hd)*Sq + s2x] = f2bf(c);
        }
      }
    }
  }
  #undef MFMA_BF16
}

// ---------------- flash attention v10 (r16 winner, FINAL): 4 q-tiles/block ----------
__global__ __launch_bounds__(256) void flash_attn(
    const u16* __restrict__ Q, const u16* __restrict__ K,
    const u16* __restrict__ VT, u16* __restrict__ C){
  __shared__ u16 Kt[128*64];    // [key][hd], 8 groups/row swizzled
  __shared__ u16 Vt[64*128];    // [hd][key], 16 groups/row swizzled
  __shared__ u16 Pl[4][16][72]; // per-wave P round-trip (C-layout -> A-layout)
  const int t = threadIdx.x;
  const int lane = t&63, wave = t>>6, quad = lane>>4, l16 = lane&15;
  // T1 remap: grid (8, 64) = 512; L&7 = XCD; per-XCD chunk = 8 bh x 8 p.
  int L  = blockIdx.x + blockIdx.y*gridDim.x;
  int k8 = L & 7, ii = L >> 3;           // ii in [0,64)
  const int bh = k8*8 + (ii>>3);
  const int p  = ii & 7;                 // [0,8)
  const int b = bh >> 4, h = bh & 15;
  const int qt[4] = { p, 15-p, 16+p, 31-p };
  int nk[4];
  #pragma unroll
  for(int tt=0;tt<4;tt++){ int v = qt[tt]+2; nk[tt] = (v<32)?v:32; }
  const int nrounds = (nk[3]+1)>>1;      // qt[3]=31-p is the max
  const u16* Qh = Q  + (size_t)bh*Sq*HDq;
  const u16* Kh = K  + (size_t)bh*Sq*HDq;
  const u16* Vh = VT + (size_t)bh*HDq*Sq;

  b16x8 aq[4][2];
  #pragma unroll
  for(int tt=0;tt<4;tt++){
    const u16* qp = Qh + (size_t)(qt[tt]*64 + wave*16 + l16)*HDq + quad*8;
    aq[tt][0] = *(const b16x8*)qp;
    aq[tt][1] = *(const b16x8*)(qp + 32);
  }
  b16x8 vone;
  #pragma unroll
  for(int i=0;i<8;i++) vone[i] = (__bf16)1.0f;

  const f32x4 fzero = {0.f,0.f,0.f,0.f};
  f32x4 Oa[4][4]; f32x4 lacc[4];
  #pragma unroll
  for(int tt=0;tt<4;tt++){ lacc[tt]=fzero; for(int j=0;j<4;j++) Oa[tt][j]=fzero; }

  for(int kt2=0; kt2<nrounds; kt2++){
    __syncthreads();
    #pragma unroll
    for(int r=0;r<4;r++){
      int idx = t + (r<<8);            // K slots 0..1023
      int row = idx>>3, g = idx&7;
      int csw = (g ^ (row&7))<<3;
      ld16(Kh + (size_t)(kt2*128+row)*HDq + csw, Kt + idx*8);
    }
    #pragma unroll
    for(int r=0;r<4;r++){
      int idx = t + (r<<8);            // V slots 0..1023
      int row = idx>>4, g = idx&15;    // 64 hd-rows x 16 groups
      int csw = (g ^ (row&15))<<3;
      ld16(Vh + (size_t)row*Sq + (size_t)kt2*128 + csw, Vt + idx*8);
    }
    __syncthreads();

    #pragma unroll
    for(int half=0; half<2; half++){
      const int kt = kt2*2 + half;
      #pragma unroll
      for(int tt=0;tt<4;tt++){
        if (kt >= nk[tt]) continue;            // wave-uniform skip
        const int qq0 = qt[tt]*64;
        f32x4 sc[4];
        #pragma unroll
        for(int jn=0;jn<4;jn++){
          int krow = half*64 + jn*16 + l16;
          const u16* kp = &Kt[krow*64];
          f32x4 s = fzero;
          b16x8 bk0 = *(const b16x8*)&kp[((quad     ^ (krow&7))<<3)];
          b16x8 bk1 = *(const b16x8*)&kp[(((quad+4) ^ (krow&7))<<3)];
          s = __builtin_amdgcn_mfma_f32_16x16x32_bf16(aq[tt][0], bk0, s, 0,0,0);
          s = __builtin_amdgcn_mfma_f32_16x16x32_bf16(aq[tt][1], bk1, s, 0,0,0);
          sc[jn] = s;
        }
        if (kt < qt[tt]) {
          // fully unmasked tile: p = exp2(s) directly (Q carries the scale)
          #pragma unroll
          for(int jn=0;jn<4;jn++)
            #pragma unroll
            for(int r=0;r<4;r++)
              Pl[wave][quad*4+r][jn*16+l16] = truncbf(EXP2(sc[jn][r]));
        } else {
          // boundary tiles kt in {qt, qt+1}: apply causal(+1) mask
          const int qbase = qq0 + wave*16 + quad*4;
          #pragma unroll
          for(int jn=0;jn<4;jn++){
            int kg = kt*64 + jn*16 + l16;
            #pragma unroll
            for(int r=0;r<4;r++){
              float sv = sc[jn][r];
              if (kg > qbase + r + 1) sv = -__builtin_inff();   // tril(k=1): key <= q+1
              Pl[wave][quad*4+r][jn*16+l16] = truncbf(EXP2(sv));
            }
          }
        }
        // O += P V ; l += P . 1   (Pl wave-private: no barrier)
        #pragma unroll
        for(int ks=0;ks<2;ks++){
          b16x8 ap = *(const b16x8*)&Pl[wave][l16][ks*32 + quad*8];
          int glog = half*8 + ks*4 + quad;
          #pragma unroll
          for(int jd=0;jd<4;jd++){
            int hd = jd*16 + l16;
            b16x8 bv = *(const b16x8*)&Vt[hd*128 + ((glog ^ (hd&15))<<3)];
            Oa[tt][jd] = __builtin_amdgcn_mfma_f32_16x16x32_bf16(ap, bv, Oa[tt][jd], 0,0,0);
          }
          lacc[tt] = __builtin_amdgcn_mfma_f32_16x16x32_bf16(ap, vone, lacc[tt], 0,0,0);
        }
      }
    }
  }
  #pragma unroll
  for(int tt=0;tt<4;tt++){
    const int qq0 = qt[tt]*64;
    #pragma unroll
    for(int r=0;r<4;r++){
      int s = qq0 + wave*16 + quad*4 + r;
      float inv = 1.0f / lacc[tt][r];
      #pragma unroll
      for(int jd=0;jd<4;jd++)
        C[((size_t)(b*Sq + s))*Dq + h*HDq + jd*16 + l16] = f2bf(Oa[tt][jd][r]*inv);
    }
  }
}

// ---------------- launch ----------------
extern "C" void kernel_launch(void* const* d_in, const int* in_sizes, int n_in,
                              void* d_out, int out_size, void* d_ws, size_t ws_size,
                              hipStream_t stream){
  const void* x  = d_in[0];
  const void* Wq = d_in[1];
  const void* Wk = d_in[2];
  const void* Wv = d_in[3];
  const void* Wo = d_in[4];
  const void* bo = d_in[5];

  char* ws = (char*)d_ws;
  size_t off = 0;
  auto wsalloc = [&](size_t bytes)->void*{
    void* p = ws + off; off += (bytes + 255) & ~(size_t)255; return p;
  };
  // WqT/WkT/WvT contiguous: QKV-gemm sees one [3072][1024] B^T matrix
  u16* WqT = (u16*)wsalloc((size_t)Dq*Dq*2);
  u16* WkT = (u16*)wsalloc((size_t)Dq*Dq*2);
  u16* WvT = (u16*)wsalloc((size_t)Dq*Dq*2);
  u16* WoT = (u16*)wsalloc((size_t)Dq*Dq*2);
  u16* xc  = (u16*)wsalloc((size_t)Mq*Dq*2);
  u16* Qb  = (u16*)wsalloc((size_t)Mq*Dq*2);   // [b,h,s,hd], pre-scaled
  u16* Kb  = (u16*)wsalloc((size_t)Mq*Dq*2);   // [b,h,s,hd]
  u16* VTb = (u16*)wsalloc((size_t)Mq*Dq*2);   // [b,h,hd,s]
  u16* Cb  = (u16*)wsalloc((size_t)Mq*Dq*2);   // [b,s,d]

  prep<<<dim3(5120), 256, 0, stream>>>(x, Wq,Wk,Wv,Wo, xc, WqT,WkT,WvT,WoT);
  gemm2p<0><<<dim3(24, 64), 256, 0, stream>>>(xc, WqT, Qb,Kb,VTb, nullptr, nullptr, nullptr);
  flash_attn<<<dim3(8, Bq*Hq), 256, 0, stream>>>(Qb, Kb, VTb, Cb);
  gemm2p<1><<<dim3(8, 64), 256, 0, stream>>>(Cb, WoT, nullptr,nullptr,nullptr, d_out, bo, (const unsigned*)x);
}

// Round 21
// 191.458 us; speedup vs baseline: 1.2437x; 1.0096x over previous
//
#include <hip/hip_runtime.h>
#include <hip/hip_bf16.h>

#define Bq 4
#define Sq 2048
#define Dq 1024
#define Hq 16
#define HDq 64
#define Mq (Bq*Sq)   // 8192

typedef unsigned short u16;
typedef __attribute__((ext_vector_type(8))) __bf16 b16x8;
typedef __attribute__((ext_vector_type(4))) float f32x4;
typedef __attribute__((ext_vector_type(4))) unsigned int u32x4;

__device__ inline float bf2f(u16 h){ union{unsigned u; float f;} v; v.u = ((unsigned)h)<<16; return v.f; }
__device__ inline u16 f2bf(float f){ union{float f; unsigned u;} v; v.f=f; unsigned r = v.u + 0x7FFFu + ((v.u>>16)&1u); return (u16)(r>>16); }
__device__ inline u16 truncbf(float f){ union{float f; unsigned u;} v; v.f=f; return (u16)(v.u>>16); }
__device__ inline float ld_elem(const void* p, size_t i, int isf32){
  return isf32 ? ((const float*)p)[i] : bf2f(((const u16*)p)[i]);
}
// async global->LDS (kept for flash; GEMMs now reg-stage)
__device__ inline void ld16(const u16* g, u16* l){
  __builtin_amdgcn_global_load_lds((const __attribute__((address_space(1))) void*)g,
                                   (__attribute__((address_space(3))) void*)l, 16, 0, 0);
}

#if __has_builtin(__builtin_amdgcn_exp2f)
#define EXP2(x) __builtin_amdgcn_exp2f(x)
#else
#define EXP2(x) __expf((x)*0.69314718056f)
#endif
// 0.125 (1/sqrt(64)) * log2(e): folded into Q in the QKV-gemm epilogue.
#define SCALE_LOG2E 0.18033688011112042f

// ---- per-wave dtype detection (verified r12-r20)
__device__ inline int detect_wave(const unsigned* __restrict__ x, int t){
  unsigned w = x[t & 255];
  unsigned long long m1 = __ballot(((w>>7)&0xFFu)>=0x90u);
  unsigned long long m2 = __ballot(((w>>23)&0xFFu)>=0x90u);
  return (__popcll(m1)+__popcll(m2)) > 8 ? 1 : 0;
}

// ---- fused preamble (verified r12-r20)
__global__ __launch_bounds__(256) void prep(
    const void* __restrict__ x,
    const void* __restrict__ W0, const void* __restrict__ W1,
    const void* __restrict__ W2, const void* __restrict__ W3,
    u16* __restrict__ xc,
    u16* __restrict__ T0, u16* __restrict__ T1,
    u16* __restrict__ T2, u16* __restrict__ T3){
  __shared__ u16 tile[64][65];
  const int t = threadIdx.x;
  const int f = detect_wave((const unsigned*)x, t);
  const int bid = blockIdx.x;
  if (bid < 4096){
    int i = (bid*256 + t)*8;                     // covers Mq*Dq exactly
    if(f){
      const float* xf=(const float*)x;
      #pragma unroll
      for(int j=0;j<8;j++) xc[i+j] = f2bf(xf[i+j]);
    } else {
      *(u32x4*)&xc[i] = *(const u32x4*)((const u16*)x + i);
    }
  } else {
    int idx = bid - 4096;                        // [0,1024)
    int z = idx >> 8, rem = idx & 255;
    int k0 = (rem & 15)*64, n0 = (rem >> 4)*64;
    const void* src = (z==0)?W0:(z==1)?W1:(z==2)?W2:W3;
    u16*       dst = (z==0)?T0:(z==1)?T1:(z==2)?T2:T3;
    #pragma unroll
    for(int r=0;r<16;r++){
      int row = r*4 + (t>>6), col = t&63;
      tile[row][col] = f2bf(ld_elem(src, (size_t)(k0+row)*Dq + n0 + col, f));
    }
    __syncthreads();
    #pragma unroll
    for(int r=0;r<16;r++){
      int row = r*4 + (t>>6), col = t&63;
      dst[(size_t)(n0+row)*Dq + k0 + col] = tile[col][row];
    }
  }
}

// ---------------- GEMM v15: r8 geometry, REG-STAGED (global->reg->ds_write) ----------------
// The one axis all 21 variants shared: staging via global_load_lds. The completed
// law shows THAT instruction is per-wave-capped (~1-2.5 B/cyc/wave, ~960 cyc per
// 1KB DMA in this cell), while plain global_load_dwordx4 measured 5-10x faster
// per wave (r12 A-direct, m13) and the traffic is 94% L2-resident (L2 BW 56 B/cyc
// /CU not binding). HK deliberately reg-stages (catalog T14/s05); m151's contrary
// result was measured in a healthy 874 TF regime, not our 500 TF pathology.
// v15 swaps ONLY the staging path: same tiles, same pre-swizzled source address,
// same linear LDS offsets (data placement bit-identical), same read side.
// T14 split pipeline (loads issued >=1 iter before their wait):
//   prologue: load(0)->reg; vmcnt0; ds_write->s0; load(1)->reg; lgkm0; bar.
//   iter tt:  vmcnt0 (tile tt+1 regs arrived, issued ~2000cyc ago);
//             ds_write reg -> s^1;  issue load(tt+2)->reg  (write reads regs at
//             issue, before load completion can overwrite -- program order);
//             ds_read s; lgkm0 (covers writes+reads); sched_barrier; MFMA;
//             bar (publishes s^1 writes, seals s reads).
// WAR s^1: readers were iter tt-1, sealed by its barrier. Ring-2 LDS (32KB).
// Reg cost: one u32x4[4] buffer = 16 VGPR -> ~90 total.
template<int MODE>
__global__ __launch_bounds__(256, 3) void gemm2p(
    const u16* __restrict__ A, const u16* __restrict__ Bt,
    u16* __restrict__ O0, u16* __restrict__ O1, u16* __restrict__ O2,
    void* __restrict__ Og, const void* __restrict__ bias,
    const unsigned* __restrict__ xdet){
  constexpr int NT = Dq/32;                      // 32 K-tiles (BK=32)
  __shared__ u16 Asl[2][128*32];
  __shared__ u16 Bsl[2][128*32];                 // 32KB total
  const int f = (MODE==1) ? detect_wave(xdet, threadIdx.x) : 0;
  const int t = threadIdx.x;
  const int lane = t & 63, wave = t >> 6;        // 4 waves
  const int quad = lane >> 4, l16 = lane & 15;
  const int wr = wave >> 1, wc = wave & 1;       // 2M x 2N
  // T1 XCD-chunked remap. nwg%8==0 for both grids (1536 / 512).
  int L = blockIdx.x + blockIdx.y*gridDim.x;
  int k8 = L & 7, ii = L >> 3;
  int m0, n0;
  if (MODE==0){
    int nsb = ii >> 6, rem = ii & 63;
    int mg = rem >> 3, ng = rem & 7;
    m0 = (k8*8 + mg)*128; n0 = (nsb*8 + ng)*128;
  } else {
    int mg = ii >> 3, ng = ii & 7;
    m0 = (k8*8 + mg)*128; n0 = ng*128;
  }

  f32x4 acc[4][4] = {};
  u32x4 rg[4];                                   // staging regs: [0..1]=A, [2..3]=B

  auto loadG = [&](int T){                       // 4 global_load_dwordx4 -> regs
    #pragma unroll
    for(int r=0;r<2;r++){
      int idx = t + (r<<8);
      int row = idx>>2, g = idx&3;
      int gl = g ^ ((row>>1)&3);                 // pre-swizzled source (unchanged)
      rg[r]   = *(const u32x4*)&A [(size_t)(m0+row)*Dq + (T<<5) + gl*8];
      rg[2+r] = *(const u32x4*)&Bt[(size_t)(n0+row)*Dq + (T<<5) + gl*8];
    }
  };
  auto writeL = [&](int s){                      // 4 ds_write_b128, linear dest
    #pragma unroll
    for(int r=0;r<2;r++){
      int idx = t + (r<<8);
      *(u32x4*)&Asl[s][idx*8] = rg[r];
      *(u32x4*)&Bsl[s][idx*8] = rg[2+r];
    }
  };
  auto ldA = [&](int s, int i)->b16x8{
    int row = wr*64 + i*16 + l16;
    return *(const b16x8*)&Asl[s][row*32 + ((quad ^ ((row>>1)&3))<<3)];
  };
  auto ldB = [&](int s, int j)->b16x8{
    int row = wc*64 + j*16 + l16;
    return *(const b16x8*)&Bsl[s][row*32 + ((quad ^ ((row>>1)&3))<<3)];
  };
  #define MFMA_BF16 __builtin_amdgcn_mfma_f32_16x16x32_bf16

  // prologue: tile 0 -> LDS; tile 1 loads in flight in regs.
  loadG(0);
  asm volatile("s_waitcnt vmcnt(0)" ::: "memory");
  writeL(0);
  loadG(1);
  asm volatile("s_waitcnt lgkmcnt(0)" ::: "memory");
  __builtin_amdgcn_s_barrier();
  __builtin_amdgcn_sched_barrier(0);

  for(int tt=0; tt<NT; ++tt){
    const int s = tt&1;
    if(tt+1<NT){
      asm volatile("s_waitcnt vmcnt(0)" ::: "memory");  // tile tt+1 regs landed
      writeL(s^1);                                       // stage tile tt+1
    }
    if(tt+2<NT) loadG(tt+2);                             // issue next (regs freed
                                                         // by writeL at its issue)
    b16x8 af[4], bf[4];
    #pragma unroll
    for(int i=0;i<4;i++) af[i]=ldA(s,i);
    #pragma unroll
    for(int j=0;j<4;j++) bf[j]=ldB(s,j);
    asm volatile("s_waitcnt lgkmcnt(0)" ::: "memory");   // reads + s^1 writes done
    __builtin_amdgcn_sched_barrier(0);                   // rule #18
    __builtin_amdgcn_s_setprio(1);
    #pragma unroll
    for(int i=0;i<4;i++)
      #pragma unroll
      for(int j=0;j<4;j++)
        acc[i][j]=MFMA_BF16(af[i],bf[j],acc[i][j],0,0,0);
    __builtin_amdgcn_s_setprio(0);
    __builtin_amdgcn_s_barrier();                        // publish s^1, seal s
    __builtin_amdgcn_sched_barrier(0);
  }

  #pragma unroll
  for(int i=0;i<4;i++){
    #pragma unroll
    for(int j=0;j<4;j++){
      int n = n0 + wc*64 + j*16 + l16;
      #pragma unroll
      for(int r=0;r<4;r++){
        int m = m0 + wr*64 + i*16 + quad*4 + r;   // C/D: row=quad*4+reg, col=l16
        float c = acc[i][j][r];
        if (MODE==1){
          float c2 = c + ld_elem(bias, n, f);
          if (f) ((float*)Og)[(size_t)m*Dq + n] = c2;
          else   ((u16*)Og)[(size_t)m*Dq + n]   = f2bf(c2);
        } else {
          int z = n >> 10, nn2 = n & 1023;
          int b = m >> 11, s2x = m & 2047;
          int h = nn2 >> 6, hd = nn2 & 63;
          if (z==0)      O0[(((size_t)(b*Hq + h))*Sq + s2x)*HDq + hd] = f2bf(c*SCALE_LOG2E);
          else if (z==1) O1[(((size_t)(b*Hq + h))*Sq + s2x)*HDq + hd] = f2bf(c);
          else           O2[(((size_t)(b*Hq + h))*HDq + hd)*Sq + s2x] = f2bf(c);
        }
      }
    }
  }
  #undef MFMA_BF16
}

// ---------------- flash attention v10 (r16 winner, verbatim): 4 q-tiles/block ----------
__global__ __launch_bounds__(256) void flash_attn(
    const u16* __restrict__ Q, const u16* __restrict__ K,
    const u16* __restrict__ VT, u16* __restrict__ C){
  __shared__ u16 Kt[128*64];    // [key][hd], 8 groups/row swizzled
  __shared__ u16 Vt[64*128];    // [hd][key], 16 groups/row swizzled
  __shared__ u16 Pl[4][16][72]; // per-wave P round-trip (C-layout -> A-layout)
  const int t = threadIdx.x;
  const int lane = t&63, wave = t>>6, quad = lane>>4, l16 = lane&15;
  // T1 remap: grid (8, 64) = 512; L&7 = XCD; per-XCD chunk = 8 bh x 8 p.
  int L  = blockIdx.x + blockIdx.y*gridDim.x;
  int k8 = L & 7, ii = L >> 3;           // ii in [0,64)
  const int bh = k8*8 + (ii>>3);
  const int p  = ii & 7;                 // [0,8)
  const int b = bh >> 4, h = bh & 15;
  const int qt[4] = { p, 15-p, 16+p, 31-p };
  int nk[4];
  #pragma unroll
  for(int tt=0;tt<4;tt++){ int v = qt[tt]+2; nk[tt] = (v<32)?v:32; }
  const int nrounds = (nk[3]+1)>>1;      // qt[3]=31-p is the max
  const u16* Qh = Q  + (size_t)bh*Sq*HDq;
  const u16* Kh = K  + (size_t)bh*Sq*HDq;
  const u16* Vh = VT + (size_t)bh*HDq*Sq;

  b16x8 aq[4][2];
  #pragma unroll
  for(int tt=0;tt<4;tt++){
    const u16* qp = Qh + (size_t)(qt[tt]*64 + wave*16 + l16)*HDq + quad*8;
    aq[tt][0] = *(const b16x8*)qp;
    aq[tt][1] = *(const b16x8*)(qp + 32);
  }
  b16x8 vone;
  #pragma unroll
  for(int i=0;i<8;i++) vone[i] = (__bf16)1.0f;

  const f32x4 fzero = {0.f,0.f,0.f,0.f};
  f32x4 Oa[4][4]; f32x4 lacc[4];
  #pragma unroll
  for(int tt=0;tt<4;tt++){ lacc[tt]=fzero; for(int j=0;j<4;j++) Oa[tt][j]=fzero; }

  for(int kt2=0; kt2<nrounds; kt2++){
    __syncthreads();
    #pragma unroll
    for(int r=0;r<4;r++){
      int idx = t + (r<<8);            // K slots 0..1023
      int row = idx>>3, g = idx&7;
      int csw = (g ^ (row&7))<<3;
      ld16(Kh + (size_t)(kt2*128+row)*HDq + csw, Kt + idx*8);
    }
    #pragma unroll
    for(int r=0;r<4;r++){
      int idx = t + (r<<8);            // V slots 0..1023
      int row = idx>>4, g = idx&15;    // 64 hd-rows x 16 groups
      int csw = (g ^ (row&15))<<3;
      ld16(Vh + (size_t)row*Sq + (size_t)kt2*128 + csw, Vt + idx*8);
    }
    __syncthreads();

    #pragma unroll
    for(int half=0; half<2; half++){
      const int kt = kt2*2 + half;
      #pragma unroll
      for(int tt=0;tt<4;tt++){
        if (kt >= nk[tt]) continue;            // wave-uniform skip
        const int qq0 = qt[tt]*64;
        f32x4 sc[4];
        #pragma unroll
        for(int jn=0;jn<4;jn++){
          int krow = half*64 + jn*16 + l16;
          const u16* kp = &Kt[krow*64];
          f32x4 s = fzero;
          b16x8 bk0 = *(const b16x8*)&kp[((quad     ^ (krow&7))<<3)];
          b16x8 bk1 = *(const b16x8*)&kp[(((quad+4) ^ (krow&7))<<3)];
          s = __builtin_amdgcn_mfma_f32_16x16x32_bf16(aq[tt][0], bk0, s, 0,0,0);
          s = __builtin_amdgcn_mfma_f32_16x16x32_bf16(aq[tt][1], bk1, s, 0,0,0);
          sc[jn] = s;
        }
        if (kt < qt[tt]) {
          // fully unmasked tile: p = exp2(s) directly (Q carries the scale)
          #pragma unroll
          for(int jn=0;jn<4;jn++)
            #pragma unroll
            for(int r=0;r<4;r++)
              Pl[wave][quad*4+r][jn*16+l16] = truncbf(EXP2(sc[jn][r]));
        } else {
          // boundary tiles kt in {qt, qt+1}: apply causal(+1) mask
          const int qbase = qq0 + wave*16 + quad*4;
          #pragma unroll
          for(int jn=0;jn<4;jn++){
            int kg = kt*64 + jn*16 + l16;
            #pragma unroll
            for(int r=0;r<4;r++){
              float sv = sc[jn][r];
              if (kg > qbase + r + 1) sv = -__builtin_inff();   // tril(k=1): key <= q+1
              Pl[wave][quad*4+r][jn*16+l16] = truncbf(EXP2(sv));
            }
          }
        }
        // O += P V ; l += P . 1   (Pl wave-private: no barrier)
        #pragma unroll
        for(int ks=0;ks<2;ks++){
          b16x8 ap = *(const b16x8*)&Pl[wave][l16][ks*32 + quad*8];
          int glog = half*8 + ks*4 + quad;
          #pragma unroll
          for(int jd=0;jd<4;jd++){
            int hd = jd*16 + l16;
            b16x8 bv = *(const b16x8*)&Vt[hd*128 + ((glog ^ (hd&15))<<3)];
            Oa[tt][jd] = __builtin_amdgcn_mfma_f32_16x16x32_bf16(ap, bv, Oa[tt][jd], 0,0,0);
          }
          lacc[tt] = __builtin_amdgcn_mfma_f32_16x16x32_bf16(ap, vone, lacc[tt], 0,0,0);
        }
      }
    }
  }
  #pragma unroll
  for(int tt=0;tt<4;tt++){
    const int qq0 = qt[tt]*64;
    #pragma unroll
    for(int r=0;r<4;r++){
      int s = qq0 + wave*16 + quad*4 + r;
      float inv = 1.0f / lacc[tt][r];
      #pragma unroll
      for(int jd=0;jd<4;jd++)
        C[((size_t)(b*Sq + s))*Dq + h*HDq + jd*16 + l16] = f2bf(Oa[tt][jd][r]*inv);
    }
  }
}

// ---------------- launch ----------------
extern "C" void kernel_launch(void* const* d_in, const int* in_sizes, int n_in,
                              void* d_out, int out_size, void* d_ws, size_t ws_size,
                              hipStream_t stream){
  const void* x  = d_in[0];
  const void* Wq = d_in[1];
  const void* Wk = d_in[2];
  const void* Wv = d_in[3];
  const void* Wo = d_in[4];
  const void* bo = d_in[5];

  char* ws = (char*)d_ws;
  size_t off = 0;
  auto wsalloc = [&](size_t bytes)->void*{
    void* p = ws + off; off += (bytes + 255) & ~(size_t)255; return p;
  };
  // WqT/WkT/WvT contiguous: QKV-gemm sees one [3072][1024] B^T matrix
  u16* WqT = (u16*)wsalloc((size_t)Dq*Dq*2);
  u16* WkT = (u16*)wsalloc((size_t)Dq*Dq*2);
  u16* WvT = (u16*)wsalloc((size_t)Dq*Dq*2);
  u16* WoT = (u16*)wsalloc((size_t)Dq*Dq*2);
  u16* xc  = (u16*)wsalloc((size_t)Mq*Dq*2);
  u16* Qb  = (u16*)wsalloc((size_t)Mq*Dq*2);   // [b,h,s,hd], pre-scaled
  u16* Kb  = (u16*)wsalloc((size_t)Mq*Dq*2);   // [b,h,s,hd]
  u16* VTb = (u16*)wsalloc((size_t)Mq*Dq*2);   // [b,h,hd,s]
  u16* Cb  = (u16*)wsalloc((size_t)Mq*Dq*2);   // [b,s,d]

  prep<<<dim3(5120), 256, 0, stream>>>(x, Wq,Wk,Wv,Wo, xc, WqT,WkT,WvT,WoT);
  gemm2p<0><<<dim3(24, 64), 256, 0, stream>>>(xc, WqT, Qb,Kb,VTb, nullptr, nullptr, nullptr);
  flash_attn<<<dim3(8, Bq*Hq), 256, 0, stream>>>(Qb, Kb, VTb, Cb);
  gemm2p<1><<<dim3(8, 64), 256, 0, stream>>>(Cb, WoT, nullptr,nullptr,nullptr, d_out, bo, (const unsigned*)x);
}